// Round 1
// baseline (146.333 us; speedup 1.0000x reference)
//
#include <hip/hip_runtime.h>
#include <math.h>

// SquaredGaussianMixture: N=2M points, D=4, K=8, scalar f32 output.
// 2-kernel structure: point_kernel (per-block f64 param prep + density products,
// per-block partial stores — no atomics, no zero-init) -> final_kernel
// (pairwise softmax/z-normaliser + cross-block reduction + output).
// Identity: sum_n d^T W d = sum_{ij} W_ij P_ij, P_ij = sum_n d_i d_j:
// hot loop only accumulates 36 symmetric products; W applied once at the end.

#define NBLK 2048

__device__ inline void chol4(const double S[4][4], double G[4][4]) {
  #pragma unroll
  for (int i = 0; i < 4; ++i) {
    #pragma unroll
    for (int j = 0; j < 4; ++j) {
      if (j > i) { G[i][j] = 0.0; continue; }
      double s = S[i][j];
      #pragma unroll
      for (int m = 0; m < 4; ++m) if (m < j) s -= G[i][m] * G[j][m];
      if (i == j) G[i][j] = sqrt(s);
      else        G[i][j] = s / G[j][j];
    }
  }
}

// force a wave-uniform float into an SGPR (params would otherwise eat VGPRs)
__device__ __forceinline__ float uniformf(float x) {
  return __int_as_float(__builtin_amdgcn_readfirstlane(__float_as_int(x)));
}

__global__ __launch_bounds__(256, 4) void point_kernel(
    const float4* __restrict__ X, const float* __restrict__ means,
    const float* __restrict__ chols, double* __restrict__ partial, int n) {
  // per-k packed params: [a2 x10 | bb x4 | cc | pad] (floats)
  __shared__ float pp[8][16];
  const int t = threadIdx.x;
  const int S = gridDim.x * blockDim.x;
  const int idx = blockIdx.x * blockDim.x + t;

  // issue first batch of loads BEFORE the param barrier: HBM latency hides
  // under the single-wave f64 prep below.
  float4 v[4];
  float kill[4];
  #pragma unroll
  for (int j = 0; j < 4; ++j) {
    const int ij = idx + j * S;
    const bool ok = ij < n;
    kill[j] = ok ? 0.0f : -1.0e30f;  // exp2(-1e30) == 0 masks invalid point
    v[j] = X[ok ? ij : 0];
  }

  if (t < 8) {
    // per-cluster prep, identical f64 math to the old prep_kernel
    const double LOG2E = 1.4426950408889634074;
    const double LN2PI = 1.8378770664093454836;
    const int k = t;
    double L[4][4], Sm[4][4];
    #pragma unroll
    for (int i = 0; i < 4; ++i)
      #pragma unroll
      for (int j = 0; j < 4; ++j)
        L[i][j] = (j <= i) ? (double)chols[k * 16 + i * 4 + j] : 0.0;
    #pragma unroll
    for (int i = 0; i < 4; ++i)
      #pragma unroll
      for (int j = 0; j < 4; ++j) {
        double s = (i == j) ? 1.0 : 0.0;
        #pragma unroll
        for (int m = 0; m < 4; ++m) s += L[i][m] * L[j][m];
        Sm[i][j] = s;
      }
    double G[4][4];
    chol4(Sm, G);
    const double logdet =
        2.0 * (log(G[0][0]) + log(G[1][1]) + log(G[2][2]) + log(G[3][3]));
    double Gi[4][4];
    #pragma unroll
    for (int j = 0; j < 4; ++j) {
      #pragma unroll
      for (int i = 0; i < 4; ++i) {
        if (i < j) { Gi[i][j] = 0.0; continue; }
        double s = (i == j) ? 1.0 : 0.0;
        #pragma unroll
        for (int m = 0; m < 4; ++m)
          if (m >= j && m < i) s -= G[i][m] * Gi[m][j];
        Gi[i][j] = s / G[i][i];
      }
    }
    double A[4][4];
    #pragma unroll
    for (int i = 0; i < 4; ++i)
      #pragma unroll
      for (int j = 0; j < 4; ++j) {
        double s = 0.0;
        #pragma unroll
        for (int m = 0; m < 4; ++m) s += Gi[m][i] * Gi[m][j];
        A[i][j] = s;
      }
    double mu[4];
    #pragma unroll
    for (int i = 0; i < 4; ++i) mu[i] = (double)means[k * 4 + i];
    double bmu[4];
    #pragma unroll
    for (int i = 0; i < 4; ++i) {
      double s = 0.0;
      #pragma unroll
      for (int j = 0; j < 4; ++j) s += A[i][j] * mu[j];
      bmu[i] = s;
    }
    double muAmu = 0.0;
    #pragma unroll
    for (int i = 0; i < 4; ++i) muAmu += mu[i] * bmu[i];
    const double logcoef = -0.5 * (4.0 * LN2PI + logdet);
    int tt = 0;
    #pragma unroll
    for (int i = 0; i < 4; ++i)
      #pragma unroll
      for (int j = i; j < 4; ++j, ++tt)
        pp[k][tt] = (float)(-0.5 * LOG2E * A[i][j] * ((i == j) ? 1.0 : 2.0));
    #pragma unroll
    for (int i = 0; i < 4; ++i) pp[k][10 + i] = (float)(LOG2E * bmu[i]);
    pp[k][14] = (float)(LOG2E * (logcoef - 0.5 * muAmu));
    pp[k][15] = 0.0f;
  }
  __syncthreads();

  // pull params to wave-uniform (SGPR) registers
  float par[8][15];
  #pragma unroll
  for (int k = 0; k < 8; ++k)
    #pragma unroll
    for (int u = 0; u < 15; ++u) par[k][u] = uniformf(pp[k][u]);

  float acc[36];
  #pragma unroll
  for (int u = 0; u < 36; ++u) acc[u] = 0.0f;

  for (int base = idx; base < n; base += 4 * S) {
    if (base != idx) {  // first batch was preloaded above
      #pragma unroll
      for (int j = 0; j < 4; ++j) {
        const int ij = base + j * S;
        const bool ok = ij < n;
        kill[j] = ok ? 0.0f : -1.0e30f;
        v[j] = X[ok ? ij : 0];
      }
    }
    float d[4][8];
    #pragma unroll
    for (int k = 0; k < 8; ++k) {
      #pragma unroll
      for (int j = 0; j < 4; ++j) {
        const float4 vv = v[j];
        // Horner-factored quadratic form: a = cc + sum_i v_i * t_i,
        // t_i = bb_i + sum_{j>=i} a2[ij] v_j  (saves the 10 p[] products)
        float t0 = fmaf(par[k][0], vv.x, par[k][10]);
        t0 = fmaf(par[k][1], vv.y, t0);
        t0 = fmaf(par[k][2], vv.z, t0);
        t0 = fmaf(par[k][3], vv.w, t0);
        float t1 = fmaf(par[k][4], vv.y, par[k][11]);
        t1 = fmaf(par[k][5], vv.z, t1);
        t1 = fmaf(par[k][6], vv.w, t1);
        float t2 = fmaf(par[k][7], vv.z, par[k][12]);
        t2 = fmaf(par[k][8], vv.w, t2);
        float t3 = fmaf(par[k][9], vv.w, par[k][13]);
        float a = par[k][14] + kill[j];
        a = fmaf(vv.x, t0, a);
        a = fmaf(vv.y, t1, a);
        a = fmaf(vv.z, t2, a);
        a = fmaf(vv.w, t3, a);
        d[j][k] = __builtin_amdgcn_exp2f(a);
      }
    }
    #pragma unroll
    for (int j = 0; j < 4; ++j) {
      int u = 0;
      #pragma unroll
      for (int a_ = 0; a_ < 8; ++a_)
        #pragma unroll
        for (int b_ = a_; b_ < 8; ++b_, ++u)
          acc[u] = fmaf(d[j][a_], d[j][b_], acc[u]);
    }
  }

  // block reduction: wave butterfly -> LDS -> plain per-block partial store
  const int lane = t & 63;
  const int wid = t >> 6;
  __shared__ float lred[4][36];
  #pragma unroll
  for (int u = 0; u < 36; ++u) {
    float vv = acc[u];
    #pragma unroll
    for (int o = 32; o > 0; o >>= 1) vv += __shfl_xor(vv, o, 64);
    if (lane == 0) lred[wid][u] = vv;
  }
  __syncthreads();
  if (t < 36) {
    const double s = (double)lred[0][t] + (double)lred[1][t] +
                     (double)lred[2][t] + (double)lred[3][t];
    partial[t * NBLK + blockIdx.x] = s;  // [u][block] layout: coalesced final read
  }
}

__global__ void final_kernel(const double* __restrict__ partial,
                             const float* __restrict__ means,
                             const float* __restrict__ chols,
                             const float* __restrict__ weights,
                             float* __restrict__ out, int n) {
  const double LN2PI = 1.8378770664093454836;
  const int t = threadIdx.x;
  __shared__ double sig[8][4][4];
  __shared__ double red[4][36];
  __shared__ double Wp[36];
  __shared__ double logz_s;

  // rebuild sigmas (cheap: no chol needed per cluster here)
  if (t < 8) {
    const int k = t;
    double L[4][4];
    #pragma unroll
    for (int i = 0; i < 4; ++i)
      #pragma unroll
      for (int j = 0; j < 4; ++j)
        L[i][j] = (j <= i) ? (double)chols[k * 16 + i * 4 + j] : 0.0;
    #pragma unroll
    for (int i = 0; i < 4; ++i)
      #pragma unroll
      for (int j = 0; j < 4; ++j) {
        double s = (i == j) ? 1.0 : 0.0;
        #pragma unroll
        for (int m = 0; m < 4; ++m) s += L[i][m] * L[j][m];
        sig[k][i][j] = s;
      }
  }

  // stripe-accumulate the per-block partials (coalesced: consecutive b per u)
  double a36[36];
  #pragma unroll
  for (int u = 0; u < 36; ++u) a36[u] = 0.0;
  for (int b = t; b < NBLK; b += 256) {
    #pragma unroll
    for (int u = 0; u < 36; ++u) a36[u] += partial[u * NBLK + b];
  }
  __syncthreads();  // sig ready; a36 done

  // cross-thread reduce of the 36 sums: wave butterfly -> LDS
  const int lane = t & 63;
  const int wid = t >> 6;
  #pragma unroll
  for (int u = 0; u < 36; ++u) {
    double vv = a36[u];
    #pragma unroll
    for (int o = 32; o > 0; o >>= 1) vv += __shfl_xor(vv, o, 64);
    if (lane == 0) red[wid][u] = vv;
  }

  // pairwise part on wave 0: one thread per (i,j) of 8x8 (old prep's 2nd half)
  if (t < 64) {
    const int i = t >> 3, j = t & 7;
    const double wij = (double)weights[i] * (double)weights[j];
    double m = wij;
    #pragma unroll
    for (int o = 32; o > 0; o >>= 1) {
      double x = __shfl_xor(m, o, 64);
      m = fmax(m, x);
    }
    const double e = exp(wij - m);
    double ssum = e;
    #pragma unroll
    for (int o = 32; o > 0; o >>= 1) ssum += __shfl_xor(ssum, o, 64);
    const double Wij = e / ssum;

    double SS[4][4];
    #pragma unroll
    for (int a = 0; a < 4; ++a)
      #pragma unroll
      for (int b = 0; b < 4; ++b) SS[a][b] = sig[i][a][b] + sig[j][a][b];
    double G2[4][4];
    chol4(SS, G2);
    const double logdetS =
        2.0 * (log(G2[0][0]) + log(G2[1][1]) + log(G2[2][2]) + log(G2[3][3]));
    double bvec[4], y[4];
    #pragma unroll
    for (int a = 0; a < 4; ++a)
      bvec[a] = (double)means[i * 4 + a] - (double)means[j * 4 + a];
    #pragma unroll
    for (int a = 0; a < 4; ++a) {
      double s = bvec[a];
      #pragma unroll
      for (int mm = 0; mm < 4; ++mm) if (mm < a) s -= G2[a][mm] * y[mm];
      y[a] = s / G2[a][a];
    }
    const double md = y[0]*y[0] + y[1]*y[1] + y[2]*y[2] + y[3]*y[3];
    double zterm = Wij * exp(-0.5 * md - 0.5 * (4.0 * LN2PI + logdetS));
    #pragma unroll
    for (int o = 32; o > 0; o >>= 1) zterm += __shfl_xor(zterm, o, 64);
    if (t == 0) logz_s = log(zterm);

    // triangular-packed weight (off-diag doubled)
    if (i <= j) {
      const int u = 8 * i - (i * (i - 1)) / 2 + (j - i);
      Wp[u] = Wij * ((i == j) ? 1.0 : 2.0);
    }
  }
  __syncthreads();  // red, Wp, logz_s ready

  if (t < 64) {
    double val = 0.0;
    if (t < 36)
      val = Wp[t] * (red[0][t] + red[1][t] + red[2][t] + red[3][t]);
    #pragma unroll
    for (int o = 32; o > 0; o >>= 1) val += __shfl_xor(val, o, 64);
    if (t == 0) out[0] = (float)(-(log(val) - logz_s) / (double)n);
  }
}

extern "C" void kernel_launch(void* const* d_in, const int* in_sizes, int n_in,
                              void* d_out, int out_size, void* d_ws, size_t ws_size,
                              hipStream_t stream) {
  const float* X       = (const float*)d_in[0];
  const float* means   = (const float*)d_in[1];
  const float* chols   = (const float*)d_in[2];
  const float* weights = (const float*)d_in[3];
  const int npoints = in_sizes[0] / 4;

  double* partial = (double*)d_ws;  // [36][NBLK] doubles = 576 KiB
  point_kernel<<<NBLK, 256, 0, stream>>>((const float4*)X, means, chols,
                                         partial, npoints);
  final_kernel<<<1, 256, 0, stream>>>(partial, means, chols, weights,
                                      (float*)d_out, npoints);
}

// Round 2
// 141.944 us; speedup vs baseline: 1.0309x; 1.0309x over previous
//
#include <hip/hip_runtime.h>
#include <math.h>

// SquaredGaussianMixture: N=2M points, D=4, K=8, scalar f32 output.
// 2-kernel structure: point_kernel (per-block f64 param prep + density products,
// per-block partial stores — no atomics, no zero-init) -> final_kernel
// (pairwise softmax/z-normaliser + cross-block reduction + output).
// Identity: sum_n d^T W d = sum_{ij} W_ij P_ij, P_ij = sum_n d_i d_j:
// hot loop only accumulates 36 symmetric products; W applied once at the end.
//
// R1 lesson: k-outer/j-inner d[4][8] kept 32 densities live -> compiler capped
// at 64 VGPR (chasing 8 waves/EU) and spilled acc[] to scratch (WRITE_SIZE
// 13.8MB vs 0.6MB expected). Fix: j-outer immediate-consume d[8] +
// amdgpu_waves_per_eu(4,4) to pin the 128-VGPR/4-wave budget.

#define NBLK 2048

__device__ inline void chol4(const double S[4][4], double G[4][4]) {
  #pragma unroll
  for (int i = 0; i < 4; ++i) {
    #pragma unroll
    for (int j = 0; j < 4; ++j) {
      if (j > i) { G[i][j] = 0.0; continue; }
      double s = S[i][j];
      #pragma unroll
      for (int m = 0; m < 4; ++m) if (m < j) s -= G[i][m] * G[j][m];
      if (i == j) G[i][j] = sqrt(s);
      else        G[i][j] = s / G[j][j];
    }
  }
}

// force a wave-uniform float into an SGPR (params would otherwise eat VGPRs)
__device__ __forceinline__ float uniformf(float x) {
  return __int_as_float(__builtin_amdgcn_readfirstlane(__float_as_int(x)));
}

__attribute__((amdgpu_waves_per_eu(4, 4)))
__global__ __launch_bounds__(256) void point_kernel(
    const float4* __restrict__ X, const float* __restrict__ means,
    const float* __restrict__ chols, double* __restrict__ partial, int n) {
  // per-k packed params: [a2 x10 | bb x4 | cc | pad] (floats)
  __shared__ float pp[8][16];
  const int t = threadIdx.x;
  const int S = gridDim.x * blockDim.x;
  const int idx = blockIdx.x * blockDim.x + t;

  // issue first batch of loads BEFORE the param barrier: HBM latency hides
  // under the single-wave f64 prep below.
  float4 v[4];
  float kill[4];
  #pragma unroll
  for (int j = 0; j < 4; ++j) {
    const int ij = idx + j * S;
    const bool ok = ij < n;
    kill[j] = ok ? 0.0f : -1.0e30f;  // exp2(-1e30) == 0 masks invalid point
    v[j] = X[ok ? ij : 0];
  }

  if (t < 8) {
    // per-cluster prep, identical f64 math to the original prep_kernel
    const double LOG2E = 1.4426950408889634074;
    const double LN2PI = 1.8378770664093454836;
    const int k = t;
    double L[4][4], Sm[4][4];
    #pragma unroll
    for (int i = 0; i < 4; ++i)
      #pragma unroll
      for (int j = 0; j < 4; ++j)
        L[i][j] = (j <= i) ? (double)chols[k * 16 + i * 4 + j] : 0.0;
    #pragma unroll
    for (int i = 0; i < 4; ++i)
      #pragma unroll
      for (int j = 0; j < 4; ++j) {
        double s = (i == j) ? 1.0 : 0.0;
        #pragma unroll
        for (int m = 0; m < 4; ++m) s += L[i][m] * L[j][m];
        Sm[i][j] = s;
      }
    double G[4][4];
    chol4(Sm, G);
    const double logdet =
        2.0 * (log(G[0][0]) + log(G[1][1]) + log(G[2][2]) + log(G[3][3]));
    double Gi[4][4];
    #pragma unroll
    for (int j = 0; j < 4; ++j) {
      #pragma unroll
      for (int i = 0; i < 4; ++i) {
        if (i < j) { Gi[i][j] = 0.0; continue; }
        double s = (i == j) ? 1.0 : 0.0;
        #pragma unroll
        for (int m = 0; m < 4; ++m)
          if (m >= j && m < i) s -= G[i][m] * Gi[m][j];
        Gi[i][j] = s / G[i][i];
      }
    }
    double A[4][4];
    #pragma unroll
    for (int i = 0; i < 4; ++i)
      #pragma unroll
      for (int j = 0; j < 4; ++j) {
        double s = 0.0;
        #pragma unroll
        for (int m = 0; m < 4; ++m) s += Gi[m][i] * Gi[m][j];
        A[i][j] = s;
      }
    double mu[4];
    #pragma unroll
    for (int i = 0; i < 4; ++i) mu[i] = (double)means[k * 4 + i];
    double bmu[4];
    #pragma unroll
    for (int i = 0; i < 4; ++i) {
      double s = 0.0;
      #pragma unroll
      for (int j = 0; j < 4; ++j) s += A[i][j] * mu[j];
      bmu[i] = s;
    }
    double muAmu = 0.0;
    #pragma unroll
    for (int i = 0; i < 4; ++i) muAmu += mu[i] * bmu[i];
    const double logcoef = -0.5 * (4.0 * LN2PI + logdet);
    int tt = 0;
    #pragma unroll
    for (int i = 0; i < 4; ++i)
      #pragma unroll
      for (int j = i; j < 4; ++j, ++tt)
        pp[k][tt] = (float)(-0.5 * LOG2E * A[i][j] * ((i == j) ? 1.0 : 2.0));
    #pragma unroll
    for (int i = 0; i < 4; ++i) pp[k][10 + i] = (float)(LOG2E * bmu[i]);
    pp[k][14] = (float)(LOG2E * (logcoef - 0.5 * muAmu));
    pp[k][15] = 0.0f;
  }
  __syncthreads();

  // pull params to wave-uniform (SGPR) registers
  float par[8][15];
  #pragma unroll
  for (int k = 0; k < 8; ++k)
    #pragma unroll
    for (int u = 0; u < 15; ++u) par[k][u] = uniformf(pp[k][u]);

  float acc[36];
  #pragma unroll
  for (int u = 0; u < 36; ++u) acc[u] = 0.0f;

  for (int base = idx; base < n; base += 4 * S) {
    if (base != idx) {  // first batch was preloaded above
      #pragma unroll
      for (int j = 0; j < 4; ++j) {
        const int ij = base + j * S;
        const bool ok = ij < n;
        kill[j] = ok ? 0.0f : -1.0e30f;
        v[j] = X[ok ? ij : 0];
      }
    }
    // j-outer: compute d[8] for ONE point, consume immediately (keeps live
    // VGPRs ~70 — no spill at the 128-reg / 4-wave budget)
    #pragma unroll
    for (int j = 0; j < 4; ++j) {
      const float4 vv = v[j];
      float d[8];
      #pragma unroll
      for (int k = 0; k < 8; ++k) {
        // Horner-factored quadratic form: a = cc + sum_i v_i * t_i,
        // t_i = bb_i + sum_{j>=i} a2[ij] v_j  (saves the 10 p[] products)
        float t0 = fmaf(par[k][0], vv.x, par[k][10]);
        t0 = fmaf(par[k][1], vv.y, t0);
        t0 = fmaf(par[k][2], vv.z, t0);
        t0 = fmaf(par[k][3], vv.w, t0);
        float t1 = fmaf(par[k][4], vv.y, par[k][11]);
        t1 = fmaf(par[k][5], vv.z, t1);
        t1 = fmaf(par[k][6], vv.w, t1);
        float t2 = fmaf(par[k][7], vv.z, par[k][12]);
        t2 = fmaf(par[k][8], vv.w, t2);
        float t3 = fmaf(par[k][9], vv.w, par[k][13]);
        float a = par[k][14] + kill[j];
        a = fmaf(vv.x, t0, a);
        a = fmaf(vv.y, t1, a);
        a = fmaf(vv.z, t2, a);
        a = fmaf(vv.w, t3, a);
        d[k] = __builtin_amdgcn_exp2f(a);
      }
      int u = 0;
      #pragma unroll
      for (int a_ = 0; a_ < 8; ++a_)
        #pragma unroll
        for (int b_ = a_; b_ < 8; ++b_, ++u)
          acc[u] = fmaf(d[a_], d[b_], acc[u]);
    }
  }

  // block reduction: wave butterfly -> LDS -> plain per-block partial store
  const int lane = t & 63;
  const int wid = t >> 6;
  __shared__ float lred[4][36];
  #pragma unroll
  for (int u = 0; u < 36; ++u) {
    float vv = acc[u];
    #pragma unroll
    for (int o = 32; o > 0; o >>= 1) vv += __shfl_xor(vv, o, 64);
    if (lane == 0) lred[wid][u] = vv;
  }
  __syncthreads();
  if (t < 36) {
    const double s = (double)lred[0][t] + (double)lred[1][t] +
                     (double)lred[2][t] + (double)lred[3][t];
    partial[t * NBLK + blockIdx.x] = s;  // [u][block] layout: coalesced final read
  }
}

__global__ void final_kernel(const double* __restrict__ partial,
                             const float* __restrict__ means,
                             const float* __restrict__ chols,
                             const float* __restrict__ weights,
                             float* __restrict__ out, int n) {
  const double LN2PI = 1.8378770664093454836;
  const int t = threadIdx.x;
  __shared__ double sig[8][4][4];
  __shared__ double red[4][36];
  __shared__ double Wp[36];
  __shared__ double logz_s;

  // rebuild sigmas (cheap: no chol needed per cluster here)
  if (t < 8) {
    const int k = t;
    double L[4][4];
    #pragma unroll
    for (int i = 0; i < 4; ++i)
      #pragma unroll
      for (int j = 0; j < 4; ++j)
        L[i][j] = (j <= i) ? (double)chols[k * 16 + i * 4 + j] : 0.0;
    #pragma unroll
    for (int i = 0; i < 4; ++i)
      #pragma unroll
      for (int j = 0; j < 4; ++j) {
        double s = (i == j) ? 1.0 : 0.0;
        #pragma unroll
        for (int m = 0; m < 4; ++m) s += L[i][m] * L[j][m];
        sig[k][i][j] = s;
      }
  }

  // stripe-accumulate the per-block partials (coalesced: consecutive b per u)
  double a36[36];
  #pragma unroll
  for (int u = 0; u < 36; ++u) a36[u] = 0.0;
  for (int b = t; b < NBLK; b += 256) {
    #pragma unroll
    for (int u = 0; u < 36; ++u) a36[u] += partial[u * NBLK + b];
  }
  __syncthreads();  // sig ready; a36 done

  // cross-thread reduce of the 36 sums: wave butterfly -> LDS
  const int lane = t & 63;
  const int wid = t >> 6;
  #pragma unroll
  for (int u = 0; u < 36; ++u) {
    double vv = a36[u];
    #pragma unroll
    for (int o = 32; o > 0; o >>= 1) vv += __shfl_xor(vv, o, 64);
    if (lane == 0) red[wid][u] = vv;
  }

  // pairwise part on wave 0: one thread per (i,j) of 8x8
  if (t < 64) {
    const int i = t >> 3, j = t & 7;
    const double wij = (double)weights[i] * (double)weights[j];
    double m = wij;
    #pragma unroll
    for (int o = 32; o > 0; o >>= 1) {
      double x = __shfl_xor(m, o, 64);
      m = fmax(m, x);
    }
    const double e = exp(wij - m);
    double ssum = e;
    #pragma unroll
    for (int o = 32; o > 0; o >>= 1) ssum += __shfl_xor(ssum, o, 64);
    const double Wij = e / ssum;

    double SS[4][4];
    #pragma unroll
    for (int a = 0; a < 4; ++a)
      #pragma unroll
      for (int b = 0; b < 4; ++b) SS[a][b] = sig[i][a][b] + sig[j][a][b];
    double G2[4][4];
    chol4(SS, G2);
    const double logdetS =
        2.0 * (log(G2[0][0]) + log(G2[1][1]) + log(G2[2][2]) + log(G2[3][3]));
    double bvec[4], y[4];
    #pragma unroll
    for (int a = 0; a < 4; ++a)
      bvec[a] = (double)means[i * 4 + a] - (double)means[j * 4 + a];
    #pragma unroll
    for (int a = 0; a < 4; ++a) {
      double s = bvec[a];
      #pragma unroll
      for (int mm = 0; mm < 4; ++mm) if (mm < a) s -= G2[a][mm] * y[mm];
      y[a] = s / G2[a][a];
    }
    const double md = y[0]*y[0] + y[1]*y[1] + y[2]*y[2] + y[3]*y[3];
    double zterm = Wij * exp(-0.5 * md - 0.5 * (4.0 * LN2PI + logdetS));
    #pragma unroll
    for (int o = 32; o > 0; o >>= 1) zterm += __shfl_xor(zterm, o, 64);
    if (t == 0) logz_s = log(zterm);

    // triangular-packed weight (off-diag doubled)
    if (i <= j) {
      const int u = 8 * i - (i * (i - 1)) / 2 + (j - i);
      Wp[u] = Wij * ((i == j) ? 1.0 : 2.0);
    }
  }
  __syncthreads();  // red, Wp, logz_s ready

  if (t < 64) {
    double val = 0.0;
    if (t < 36)
      val = Wp[t] * (red[0][t] + red[1][t] + red[2][t] + red[3][t]);
    #pragma unroll
    for (int o = 32; o > 0; o >>= 1) val += __shfl_xor(val, o, 64);
    if (t == 0) out[0] = (float)(-(log(val) - logz_s) / (double)n);
  }
}

extern "C" void kernel_launch(void* const* d_in, const int* in_sizes, int n_in,
                              void* d_out, int out_size, void* d_ws, size_t ws_size,
                              hipStream_t stream) {
  const float* X       = (const float*)d_in[0];
  const float* means   = (const float*)d_in[1];
  const float* chols   = (const float*)d_in[2];
  const float* weights = (const float*)d_in[3];
  const int npoints = in_sizes[0] / 4;

  double* partial = (double*)d_ws;  // [36][NBLK] doubles = 576 KiB
  point_kernel<<<NBLK, 256, 0, stream>>>((const float4*)X, means, chols,
                                         partial, npoints);
  final_kernel<<<1, 256, 0, stream>>>(partial, means, chols, weights,
                                      (float*)d_out, npoints);
}